// Round 11
// baseline (300.200 us; speedup 1.0000x reference)
//
#include <hip/hip_runtime.h>
#include <cstdint>
#include <cstddef>

typedef float  floatx4 __attribute__((ext_vector_type(4)));
typedef __bf16 bf16x8  __attribute__((ext_vector_type(8)));
typedef unsigned short bf_t;
typedef unsigned int   u32;

#define NB   8
#define SEQ  2048
#define DIM  512
#define SCALE 0.04419417382415922f   // 1/sqrt(512)

__device__ __forceinline__ bf_t f2bf(float f) {
    u32 u = __builtin_bit_cast(u32, f);
    u += 0x7fffu + ((u >> 16) & 1u);   // RNE
    return (bf_t)(u >> 16);
}
__device__ __forceinline__ float bf2f(bf_t h) {
    u32 u = (u32)h << 16;
    return __builtin_bit_cast(float, u);
}

typedef const __attribute__((address_space(1))) u32* gas_t;
typedef __attribute__((address_space(3))) u32* las_t;
#define GLDS(src, dst) __builtin_amdgcn_global_load_lds((gas_t)(src), (las_t)(dst), 16, 0, 0)

// Constraint map (R9-R15, measured):
//   - R7 race rule (all K-loops): counted "s_waitcnt vmcnt(N) lgkmcnt(0)"
//     BEFORE raw s_barrier; stage kt+2 after barrier into slot read at kt-1.
//   - R9 spill was the MONOLITHIC phase (af[8]+bfr[4]+acc[32] live), not
//     acc[32] itself -> R16 splits inner loop into two 16-MFMA groups with
//     af[4] live at a time (groups read disjoint LDS; no extra barriers).
//   - R13: 8-iter K-loops can't amortize fill/drain+epilogue -> keep BK=32
//     (16 iters) for K=512 GEMMs.
//   - R15: thin 16-MFMA phases gain little; the lever is MFMA/barrier/wave.
// R16: scores -> 256x256 tile, 8 waves 2M x 4N (wave 128x64, acc[32]),
//   BK=32, 3-stage ring 96KB (1 block/CU), vmcnt(4) (4 GLDS/thread/stage).
//   32 MFMA/iter/wave (2x R14), staged bytes/FLOP 0.67x. Epilogue = psum/
//   atomics once, then two M-half smem[128][256] passes (R9's hh pattern).
//   Grid 512: xcd gets one (b,bm) x 8 bn (K 2MB fits L2). Spill tripwire:
//   VGPR>=256 or WRITE>>74MB -> revert to R14 scores.
//   Also: prep_w folded into prep_x launch (one fewer serialized dispatch).
//   pv (R15 phased) / proj byte-identical controls.
// Swizzles (measured conflict-free): BK=32 4-slot sigma(r)=(r>>1)&3 (R8);
//   BK=64 8-slot sigma(r)=r&7 (R5/R12). Realized on GLDS *source* (m104).

// ---------------------------------------------------------------------------
// prep: blocks 0..2047 = prep_x (x fp32 -> xbf + xT); 2048..2175 = prep_w
// (W2[n][k] = W[k][n] bf16, rows 0..511 Wq^T, 512..1023 Wk^T); 2176 = biases.
// ---------------------------------------------------------------------------
__global__ __launch_bounds__(256) void prep(const float* __restrict__ x,
                                            const float* __restrict__ Wq,
                                            const float* __restrict__ Wk,
                                            const float* __restrict__ bq,
                                            const float* __restrict__ bk,
                                            bf_t* __restrict__ xbf,
                                            bf_t* __restrict__ xT,
                                            bf_t* __restrict__ W2,
                                            float* __restrict__ b2) {
    __shared__ bf_t lt[64 * 72];
    const int bidx = blockIdx.x, t = threadIdx.x;
    if (bidx < 2048) {
        const int dt = bidx & 7, st = (bidx >> 3) & 31, b = bidx >> 8;
        const int s0 = st * 64, d0 = dt * 64;
#pragma unroll
        for (int i = 0; i < 4; i++) {
            int G = i * 256 + t;
            int srow = G >> 4, f4 = G & 15;
            const float4 v = *(const float4*)(x + ((size_t)(b * SEQ + s0 + srow) * DIM + d0 + f4 * 4));
            bf_t u0 = f2bf(v.x), u1 = f2bf(v.y), u2 = f2bf(v.z), u3 = f2bf(v.w);
            *(ushort4*)(xbf + (size_t)(b * SEQ + s0 + srow) * DIM + d0 + f4 * 4) =
                make_ushort4(u0, u1, u2, u3);
            lt[(f4 * 4 + 0) * 72 + srow] = u0;
            lt[(f4 * 4 + 1) * 72 + srow] = u1;
            lt[(f4 * 4 + 2) * 72 + srow] = u2;
            lt[(f4 * 4 + 3) * 72 + srow] = u3;
        }
        __syncthreads();
#pragma unroll
        for (int i = 0; i < 2; i++) {
            int G = i * 256 + t;
            int drow = G >> 3, g = G & 7;
            bf16x8 vv = *(const bf16x8*)(lt + drow * 72 + g * 8);
            *(bf16x8*)(xT + ((size_t)(b * DIM + d0 + drow) * SEQ + s0 + g * 8)) = vv;
        }
        return;
    }
    const int idx = bidx - 2048;
    if (idx == 128) {
        b2[t]       = bq[t];
        b2[t + 256] = bq[t + 256];
        b2[512 + t] = bk[t];
        b2[768 + t] = bk[t + 256];
        return;
    }
    const float* W = (idx < 64) ? Wq : Wk;
    const int nbase = (idx < 64) ? 0 : 512;
    const int w = idx & 63;
    const int kt = w & 7, nt = w >> 3;
    const int k0 = kt * 64, n0 = nt * 64;
#pragma unroll
    for (int i = 0; i < 4; i++) {
        int G = i * 256 + t;
        int krow = G >> 4, f4 = G & 15;
        const float4 v = *(const float4*)(W + ((size_t)(k0 + krow) * DIM + n0 + f4 * 4));
        lt[(f4 * 4 + 0) * 72 + krow] = f2bf(v.x);
        lt[(f4 * 4 + 1) * 72 + krow] = f2bf(v.y);
        lt[(f4 * 4 + 2) * 72 + krow] = f2bf(v.z);
        lt[(f4 * 4 + 3) * 72 + krow] = f2bf(v.w);
    }
    __syncthreads();
#pragma unroll
    for (int i = 0; i < 2; i++) {
        int G = i * 256 + t;
        int nrow = G >> 3, g = G & 7;
        bf16x8 vv = *(const bf16x8*)(lt + nrow * 72 + g * 8);
        *(bf16x8*)(W2 + ((size_t)(nbase + n0 + nrow) * DIM + k0 + g * 8)) = vv;
    }
}

// ---------------------------------------------------------------------------
// proj: C[16384 x 1024] = xbf @ W2^T + b2 ; 128x256 tile, 512 thr / 8 waves,
// BK=32, 3-stage ring (72 KB), vmcnt(3). grid (512) XCD-mapped.
// Q epilogue pre-scales by SCALE (R11).  [byte-identical: control]
// ---------------------------------------------------------------------------
__global__ __launch_bounds__(512, 4) void proj(const bf_t* __restrict__ xbf,
                                               const bf_t* __restrict__ W2,
                                               const float* __restrict__ b2,
                                               bf_t* __restrict__ Qb,
                                               bf_t* __restrict__ Kb) {
    __shared__ bf_t smem[36864];           // 72 KB: 3 x (A[128][32] | B[256][32])
    const int gid = blockIdx.x;
    const int xcd = gid & 7, rr = gid >> 3;
    const int bm = xcd * 16 + (rr >> 2), bn = rr & 3;
    const int m0 = bm * 128, n0 = bn * 256;
    const int t = threadIdx.x, w = t >> 6, lane = t & 63;
    const int col = lane & 15, quad = lane >> 4;
    const int wm = (w & 1) * 64, wn = (w >> 1) * 64;
    const int sA = (quad ^ ((col >> 1) & 3)) * 8;
    const int srow = t >> 2, sslot = t & 3;
    const int c0 = (sslot ^ ((srow >> 1) & 3)) * 8;
    bf_t *p0 = smem, *p1 = smem + 12288, *p2 = smem + 24576;
    auto stage = [&](int s, bf_t* db) {
        const int k0 = s * 32 + c0;
        GLDS(xbf + (size_t)(m0 + srow) * DIM + k0,       db + t * 8);
        GLDS(W2  + (size_t)(n0 + srow) * DIM + k0,       db + 4096 + t * 8);
        GLDS(W2  + (size_t)(n0 + 128 + srow) * DIM + k0, db + 8192 + t * 8);
    };
    stage(0, p0); stage(1, p1);
    floatx4 acc[16] = {};
    for (int kt = 0; kt < 16; kt++) {
        if (kt < 15) { asm volatile("s_waitcnt vmcnt(3) lgkmcnt(0)" ::: "memory"); }
        else         { asm volatile("s_waitcnt vmcnt(0) lgkmcnt(0)" ::: "memory"); }
        __builtin_amdgcn_s_barrier();
        if (kt < 14) stage(kt + 2, p2);
        const bf_t* as_ = p0;
        const bf_t* bs_ = p0 + 4096;
        bf16x8 af[4], bfr[4];
#pragma unroll
        for (int mt = 0; mt < 4; mt++)
            af[mt] = *(const bf16x8*)(as_ + (wm + mt * 16 + col) * 32 + sA);
#pragma unroll
        for (int nt = 0; nt < 4; nt++)
            bfr[nt] = *(const bf16x8*)(bs_ + (wn + nt * 16 + col) * 32 + sA);
#pragma unroll
        for (int mt = 0; mt < 4; mt++)
#pragma unroll
            for (int nt = 0; nt < 4; nt++)
                acc[mt * 4 + nt] = __builtin_amdgcn_mfma_f32_16x16x32_bf16(
                    af[mt], bfr[nt], acc[mt * 4 + nt], 0, 0, 0);
        bf_t* tp = p0; p0 = p1; p1 = p2; p2 = tp;
    }
    float bias[4];
#pragma unroll
    for (int nt = 0; nt < 4; nt++) bias[nt] = b2[n0 + wn + nt * 16 + col];
    const float sc = (bn < 2) ? SCALE : 1.0f;   // R11: pre-scale Q
    __syncthreads();
#pragma unroll
    for (int mt = 0; mt < 4; mt++)
#pragma unroll
        for (int nt = 0; nt < 4; nt++)
#pragma unroll
            for (int r = 0; r < 4; r++)
                smem[(wm + mt * 16 + quad * 4 + r) * 256 + wn + nt * 16 + col] =
                    f2bf((acc[mt * 4 + nt][r] + bias[nt]) * sc);
    __syncthreads();
    bf_t* dst = (bn < 2) ? Qb : Kb;
    const int nadj = (bn < 2) ? n0 : (n0 - 512);
#pragma unroll
    for (int i = 0; i < 8; i++) {
        int idx = (i * 512 + t) * 8;
        int row = idx >> 8, cg = idx & 255;
        *(bf16x8*)(dst + (size_t)(m0 + row) * DIM + nadj + cg) = *(const bf16x8*)(smem + idx);
    }
}

// ---------------------------------------------------------------------------
// scores: per batch S' = (Q*SCALE) K^T; R16: 256x256 tile, 512 thr / 8 waves
// (2M x 4N, wave 128x64, acc[32]), BK=32, 3-stage ring 96 KB, vmcnt(4),
// 16 iters, 32 MFMA/iter/wave in two 16-MFMA groups (af[4] live at a time).
// grid (512): xcd = one (b,bm) x 8 bn sharers (K 2MB fits L2).
// epilogue exp -> P' bf16 + l; two M-half smem passes.
// ---------------------------------------------------------------------------
__global__ __launch_bounds__(512, 1) void scores(const bf_t* __restrict__ Qb,
                                                 const bf_t* __restrict__ Kb,
                                                 bf_t* __restrict__ P,
                                                 float* __restrict__ l) {
    __shared__ bf_t smem[49152];           // 96 KB: 3 x (A[256][32] | B[256][32])
    const int gid = blockIdx.x;
    const int xcd = gid & 7, rr = gid >> 3;      // rr in [0,64)
    const int j = rr & 7, h = rr >> 3;           // j = bn, h in [0,8)
    const int sup = xcd + 8 * h;                 // [0,64)
    const int b = sup >> 3, bm = sup & 7;
    const int bn = j;
    const int m0 = bm * 256, n0 = bn * 256;
    const int t = threadIdx.x, w = t >> 6, lane = t & 63;
    const int col = lane & 15, quad = lane >> 4;
    const int wm = (w & 1) * 128, wn = (w >> 1) * 64;   // wave tile 128x64
    const int sA = (quad ^ ((col >> 1) & 3)) * 8;
    const int srow = t >> 2, sslot = t & 3;             // srow 0..127
    const int c0 = (sslot ^ ((srow >> 1) & 3)) * 8;     // sigma(r+128)==sigma(r)
    const bf_t* Ab = Qb + (size_t)b * SEQ * DIM;
    const bf_t* Bb = Kb + (size_t)b * SEQ * DIM;
    bf_t *p0 = smem, *p1 = smem + 16384, *p2 = smem + 32768;
    auto stage = [&](int s, bf_t* db) {
        const int k0 = s * 32 + c0;
        GLDS(Ab + (size_t)(m0 + srow) * DIM + k0,        db + t * 8);
        GLDS(Ab + (size_t)(m0 + 128 + srow) * DIM + k0,  db + 4096 + t * 8);
        GLDS(Bb + (size_t)(n0 + srow) * DIM + k0,        db + 8192 + t * 8);
        GLDS(Bb + (size_t)(n0 + 128 + srow) * DIM + k0,  db + 12288 + t * 8);
    };
    stage(0, p0); stage(1, p1);
    floatx4 acc[32] = {};
    for (int kt = 0; kt < 16; kt++) {
        if (kt < 15) { asm volatile("s_waitcnt vmcnt(4) lgkmcnt(0)" ::: "memory"); }
        else         { asm volatile("s_waitcnt vmcnt(0) lgkmcnt(0)" ::: "memory"); }
        __builtin_amdgcn_s_barrier();
        if (kt < 14) stage(kt + 2, p2);
        const bf_t* as_ = p0;                 // A rows 0..255 at row*32
        const bf_t* bs_ = p0 + 8192;          // B rows 0..255 at row*32
        // group 0: mt 0..3 (af[4] live), 16 MFMA
        {
            bf16x8 af[4], bfr[4];
#pragma unroll
            for (int mt = 0; mt < 4; mt++)
                af[mt] = *(const bf16x8*)(as_ + (wm + mt * 16 + col) * 32 + sA);
#pragma unroll
            for (int nt = 0; nt < 4; nt++)
                bfr[nt] = *(const bf16x8*)(bs_ + (wn + nt * 16 + col) * 32 + sA);
#pragma unroll
            for (int mt = 0; mt < 4; mt++)
#pragma unroll
                for (int nt = 0; nt < 4; nt++)
                    acc[mt * 4 + nt] = __builtin_amdgcn_mfma_f32_16x16x32_bf16(
                        af[mt], bfr[nt], acc[mt * 4 + nt], 0, 0, 0);
        }
        // group 1: mt 4..7
        {
            bf16x8 af[4], bfr[4];
#pragma unroll
            for (int mt = 0; mt < 4; mt++)
                af[mt] = *(const bf16x8*)(as_ + (wm + 64 + mt * 16 + col) * 32 + sA);
#pragma unroll
            for (int nt = 0; nt < 4; nt++)
                bfr[nt] = *(const bf16x8*)(bs_ + (wn + nt * 16 + col) * 32 + sA);
#pragma unroll
            for (int mt = 0; mt < 4; mt++)
#pragma unroll
                for (int nt = 0; nt < 4; nt++)
                    acc[16 + mt * 4 + nt] = __builtin_amdgcn_mfma_f32_16x16x32_bf16(
                        af[mt], bfr[nt], acc[16 + mt * 4 + nt], 0, 0, 0);
        }
        bf_t* tp = p0; p0 = p1; p1 = p2; p2 = tp;
    }
    // epilogue: exp (Q pre-scaled; no max subtraction, |s'| <= ~2.5), round to
    // bf16 (psum sums what pv consumes). acc index: g*16 + mt*4 + nt,
    // row = m0 + wm + g*64 + mt*16 + quad*4 + r, col = n0 + wn + nt*16 + col.
    float psum[8][4];
#pragma unroll
    for (int g = 0; g < 8; g++)
#pragma unroll
        for (int r = 0; r < 4; r++) psum[g][r] = 0.f;
#pragma unroll
    for (int g = 0; g < 2; g++)
#pragma unroll
        for (int mt = 0; mt < 4; mt++)
#pragma unroll
            for (int nt = 0; nt < 4; nt++)
#pragma unroll
                for (int r = 0; r < 4; r++) {
                    float e = __expf(acc[g * 16 + mt * 4 + nt][r]);
                    float ef = bf2f(f2bf(e));
                    acc[g * 16 + mt * 4 + nt][r] = ef;
                    psum[g * 4 + mt][r] += ef;
                }
#pragma unroll
    for (int g = 0; g < 8; g++)
#pragma unroll
        for (int r = 0; r < 4; r++) {
            float v = psum[g][r];
            v += __shfl_xor(v, 1);
            v += __shfl_xor(v, 2);
            v += __shfl_xor(v, 4);
            v += __shfl_xor(v, 8);
            psum[g][r] = v;
        }
    if (col == 0) {
#pragma unroll
        for (int g = 0; g < 8; g++)
#pragma unroll
            for (int r = 0; r < 4; r++)
                atomicAdd(&l[(size_t)b * SEQ + m0 + wm + g * 16 + quad * 4 + r],
                          psum[g][r]);
    }
    // two M-half passes through smem[128][256]
#pragma unroll
    for (int hh = 0; hh < 2; hh++) {
        __syncthreads();
        if ((w & 1) == hh) {
#pragma unroll
            for (int g = 0; g < 2; g++)
#pragma unroll
                for (int mt = 0; mt < 4; mt++)
#pragma unroll
                    for (int nt = 0; nt < 4; nt++)
#pragma unroll
                        for (int r = 0; r < 4; r++)
                            smem[(g * 64 + mt * 16 + quad * 4 + r) * 256 +
                                 wn + nt * 16 + col] =
                                f2bf(acc[g * 16 + mt * 4 + nt][r]);
        }
        __syncthreads();
#pragma unroll
        for (int i = 0; i < 8; i++) {
            int idx = (i * 512 + t) * 8;
            int row = idx >> 8, cg = idx & 255;
            *(bf16x8*)(P + (size_t)(b * SEQ + m0 + hh * 128 + row) * SEQ + n0 + cg) =
                *(const bf16x8*)(smem + idx);
        }
    }
}

// ---------------------------------------------------------------------------
// pv: per batch out = (P' @ x) / l  (M=2048, N=512, K=2048). B = xT (k-contig).
// R15: R12 geometry (256x128 tile, 8 waves 4Mx2N, BK=64, 3-stage 144KB ring,
// grid 256, b=gid&7) with phase-split schedule. [byte-identical: control]
// ---------------------------------------------------------------------------
__global__ __launch_bounds__(512, 1) void pv(const bf_t* __restrict__ P,
                                             const bf_t* __restrict__ xT,
                                             const float* __restrict__ l,
                                             float* __restrict__ out) {
    __shared__ bf_t smem[73728];           // 144 KB: 3 x 24576
    const int gid = blockIdx.x;
    const int b = gid & 7;
    const int inner = gid >> 3;            // [0,32)
    const int bm = inner >> 2, bn = inner & 3;
    const int m0 = bm * 256, n0 = bn * 128;
    const int t = threadIdx.x, w = t >> 6, lane = t & 63;
    const int col = lane & 15, quad = lane >> 4;
    const int wm = (w & 3) * 64, wn = (w >> 2) * 64;
    const int sA = (quad ^ (col & 7)) * 8;            // read slot, kc=0; kc=1 at ^32
    const int srow = t >> 3, sslot = t & 7;           // staging: row, slot
    const int c0 = (sslot ^ (srow & 7)) * 8;          // source chunk offset
    const bf_t* Ab = P  + (size_t)b * SEQ * SEQ;
    const bf_t* Bb = xT + (size_t)b * DIM * SEQ;
    auto stageA = [&](int s) {
        bf_t* db = smem + (s % 3) * 24576;
        const int k0 = s * 64 + c0;
        GLDS(Ab + (size_t)(m0 + srow) * SEQ + k0,        db + t * 8);
        GLDS(Ab + (size_t)(m0 + 64 + srow) * SEQ + k0,   db + 4096 + t * 8);
        GLDS(Ab + (size_t)(m0 + 128 + srow) * SEQ + k0,  db + 8192 + t * 8);
    };
    auto stageB = [&](int s) {
        bf_t* db = smem + (s % 3) * 24576;
        const int k0 = s * 64 + c0;
        GLDS(Ab + (size_t)(m0 + 192 + srow) * SEQ + k0,  db + 12288 + t * 8);
        GLDS(Bb + (size_t)(n0 + srow) * SEQ + k0,        db + 16384 + t * 8);
        GLDS(Bb + (size_t)(n0 + 64 + srow) * SEQ + k0,   db + 20480 + t * 8);
    };
    stageA(0); stageB(0); stageA(1); stageB(1);
    floatx4 acc[16] = {};

#define PV_PHASE(as_, bs_, KOFF, GLDS_SLICE, TRAIL_BARRIER)                    \
    {                                                                          \
        bf16x8 af[4], bfr[4];                                                  \
        _Pragma("unroll")                                                      \
        for (int mt = 0; mt < 4; mt++)                                         \
            af[mt] = *(const bf16x8*)((as_) + (wm + mt * 16 + col) * 64 +      \
                                      (sA ^ (KOFF)));                          \
        _Pragma("unroll")                                                      \
        for (int nt = 0; nt < 4; nt++)                                         \
            bfr[nt] = *(const bf16x8*)((bs_) + (wn + nt * 16 + col) * 64 +     \
                                       (sA ^ (KOFF)));                         \
        GLDS_SLICE;                                                            \
        __builtin_amdgcn_s_barrier();                                          \
        asm volatile("s_waitcnt lgkmcnt(0)" ::: "memory");                     \
        __builtin_amdgcn_sched_barrier(0);                                     \
        __builtin_amdgcn_s_setprio(1);                                         \
        _Pragma("unroll")                                                      \
        for (int mt = 0; mt < 4; mt++)                                         \
            _Pragma("unroll")                                                  \
            for (int nt = 0; nt < 4; nt++)                                     \
                acc[mt * 4 + nt] = __builtin_amdgcn_mfma_f32_16x16x32_bf16(    \
                    af[mt], bfr[nt], acc[mt * 4 + nt], 0, 0, 0);               \
        __builtin_amdgcn_s_setprio(0);                                         \
        if (TRAIL_BARRIER) __builtin_amdgcn_s_barrier();                       \
    }

    for (int k2 = 0; k2 < 16; k2++) {
        asm volatile("s_waitcnt vmcnt(6) lgkmcnt(0)" ::: "memory");
        __builtin_amdgcn_s_barrier();
        {
            const bf_t* as_ = smem + ((2 * k2) % 3) * 24576;
            const bf_t* bs_ = as_ + 16384;
            PV_PHASE(as_, bs_, 0,  { if (k2 < 15) stageA(2 * k2 + 2); }, 1)
            PV_PHASE(as_, bs_, 32, { if (k2 < 15) stageB(2 * k2 + 2); }, 0)
        }
        if (k2 < 15) { asm volatile("s_waitcnt vmcnt(6) lgkmcnt(0)" ::: "memory"); }
        else         { asm volatile("s_waitcnt vmcnt(0) lgkmcnt(0)" ::: "memory"); }
        __builtin_amdgcn_s_barrier();
        {
            const bf_t* as_ = smem + ((2 * k2 + 1) % 3) * 24576;
            const bf_t* bs_ = as_ + 16384;
            PV_PHASE(as_, bs_, 0,  { if (k2 < 15) stageA(2 * k2 + 3); }, 1)
            PV_PHASE(as_, bs_, 32, { if (k2 < 15) stageB(2 * k2 + 3); }, 0)
        }
    }
#undef PV_PHASE

    float inv[4][4];
#pragma unroll
    for (int mt = 0; mt < 4; mt++)
#pragma unroll
        for (int r = 0; r < 4; r++)
            inv[mt][r] = 1.0f / l[(size_t)b * SEQ + m0 + wm + mt * 16 + quad * 4 + r];
#pragma unroll
    for (int mt = 0; mt < 4; mt++)
#pragma unroll
        for (int nt = 0; nt < 4; nt++)
#pragma unroll
            for (int r = 0; r < 4; r++) {
                int row = m0 + wm + mt * 16 + quad * 4 + r;
                int cc  = n0 + wn + nt * 16 + col;
                float v = acc[mt * 4 + nt][r] * inv[mt][r];
                __builtin_nontemporal_store(v, &out[(size_t)(b * SEQ + row) * DIM + cc]);
            }
}

// ---------------------------------------------------------------------------
extern "C" void kernel_launch(void* const* d_in, const int* in_sizes, int n_in,
                              void* d_out, int out_size, void* d_ws, size_t ws_size,
                              hipStream_t stream) {
    (void)in_sizes; (void)n_in; (void)out_size;
    const float* x  = (const float*)d_in[0];
    const float* Wq = (const float*)d_in[1];
    const float* bq = (const float*)d_in[2];
    const float* Wk = (const float*)d_in[3];
    const float* bk = (const float*)d_in[4];
    float* out = (float*)d_out;

    char* ws = (char*)d_ws;
    const size_t SZ_XBF = (size_t)NB * SEQ * DIM * 2;   // 16.78 MB
    const size_t SZ_P   = (size_t)NB * SEQ * SEQ * 2;   // 67.1 MB
    bf_t* xbf = (bf_t*)(ws + 0);
    bf_t* xT  = (bf_t*)(ws + SZ_XBF);
    bf_t* Qb  = (bf_t*)(ws + 2 * SZ_XBF);
    bf_t* Kb  = (bf_t*)(ws + 3 * SZ_XBF);
    bf_t* P   = (bf_t*)(ws + 4 * SZ_XBF);
    bf_t* W2  = (bf_t*)(ws + 4 * SZ_XBF + SZ_P);
    float* b2 = (float*)(ws + 4 * SZ_XBF + SZ_P + 1024 * 512 * 2);
    float* l  = (float*)(ws + 4 * SZ_XBF + SZ_P + 1024 * 512 * 2 + 4096);
    const size_t NEED = 4 * SZ_XBF + SZ_P + 1024 * 512 * 2 + 4096 + (size_t)NB * SEQ * 4;
    if (ws_size < NEED) return;   // failure signature: absmax 0.1475 => ws too small

    hipMemsetAsync(l, 0, (size_t)NB * SEQ * 4, stream);
    prep<<<dim3(2177), dim3(256), 0, stream>>>(x, Wq, Wk, bq, bk, xbf, xT, W2, b2);
    proj<<<dim3(512), dim3(512), 0, stream>>>(xbf, W2, b2, Qb, Kb);
    scores<<<dim3(512), dim3(512), 0, stream>>>(Qb, Kb, P, l);
    pv<<<dim3(256), dim3(512), 0, stream>>>(P, xT, l, out);
}

// Round 12
// 199.696 us; speedup vs baseline: 1.5033x; 1.5033x over previous
//
#include <hip/hip_runtime.h>
#include <cstdint>
#include <cstddef>

typedef float  floatx4 __attribute__((ext_vector_type(4)));
typedef __bf16 bf16x8  __attribute__((ext_vector_type(8)));
typedef unsigned short bf_t;
typedef unsigned int   u32;

#define NB   8
#define SEQ  2048
#define DIM  512
#define SCALE 0.04419417382415922f   // 1/sqrt(512)

__device__ __forceinline__ bf_t f2bf(float f) {
    u32 u = __builtin_bit_cast(u32, f);
    u += 0x7fffu + ((u >> 16) & 1u);   // RNE
    return (bf_t)(u >> 16);
}
__device__ __forceinline__ float bf2f(bf_t h) {
    u32 u = (u32)h << 16;
    return __builtin_bit_cast(float, u);
}

typedef const __attribute__((address_space(1))) u32* gas_t;
typedef __attribute__((address_space(3))) u32* las_t;
#define GLDS(src, dst) __builtin_amdgcn_global_load_lds((gas_t)(src), (las_t)(dst), 16, 0, 0)

// R17: REVERT scores to R14 (R16 256x256/acc[32] spilled AGAIN despite
//   grouped inner loop: WRITE 74->154MB, FETCH 49->114MB, 153us. The
//   acc[16]-max rule is about the WAVE TILE, not inner-loop structure).
// Final constraint map (R6-R16, all measured):
//   - short-K GEMM (K=512, 16 iters): 128x256 tile, 2 blocks/CU, BK=32,
//     72KB ring, vmcnt(3)  [proj, scores; ~25% MfmaUtil, 53-56us scores]
//   - long-K GEMM (K=2048, 32 iters): 256x128 tile, 1 block/CU, BK=64,
//     144KB ring, vmcnt(6), phase-split  [pv; ~45us]
//   - acc[16]/wave MAX (R9+R16: acc[32] spills regardless of grouping)
//   - BK=64 at 8 iters can't amortize (R13); staging stays GLDS (R4)
//   - R7 race rule: counted "s_waitcnt vmcnt(N) lgkmcnt(0)" BEFORE raw
//     s_barrier; stage kt+2 issued after barrier into slot read at kt-1.
//   - swizzles (measured free): BK=32 sigma(r)=(r>>1)&3; BK=64 sigma(r)=r&7;
//     realized on GLDS *source* (dest linear, m104).
//   prep fusion (R16) kept: one fewer serialized dispatch, profile-clean.

// ---------------------------------------------------------------------------
// prep: blocks 0..2047 = prep_x (x fp32 -> xbf + xT); 2048..2175 = prep_w
// (W2[n][k] = W[k][n] bf16, rows 0..511 Wq^T, 512..1023 Wk^T); 2176 = biases.
// ---------------------------------------------------------------------------
__global__ __launch_bounds__(256) void prep(const float* __restrict__ x,
                                            const float* __restrict__ Wq,
                                            const float* __restrict__ Wk,
                                            const float* __restrict__ bq,
                                            const float* __restrict__ bk,
                                            bf_t* __restrict__ xbf,
                                            bf_t* __restrict__ xT,
                                            bf_t* __restrict__ W2,
                                            float* __restrict__ b2) {
    __shared__ bf_t lt[64 * 72];
    const int bidx = blockIdx.x, t = threadIdx.x;
    if (bidx < 2048) {
        const int dt = bidx & 7, st = (bidx >> 3) & 31, b = bidx >> 8;
        const int s0 = st * 64, d0 = dt * 64;
#pragma unroll
        for (int i = 0; i < 4; i++) {
            int G = i * 256 + t;
            int srow = G >> 4, f4 = G & 15;
            const float4 v = *(const float4*)(x + ((size_t)(b * SEQ + s0 + srow) * DIM + d0 + f4 * 4));
            bf_t u0 = f2bf(v.x), u1 = f2bf(v.y), u2 = f2bf(v.z), u3 = f2bf(v.w);
            *(ushort4*)(xbf + (size_t)(b * SEQ + s0 + srow) * DIM + d0 + f4 * 4) =
                make_ushort4(u0, u1, u2, u3);
            lt[(f4 * 4 + 0) * 72 + srow] = u0;
            lt[(f4 * 4 + 1) * 72 + srow] = u1;
            lt[(f4 * 4 + 2) * 72 + srow] = u2;
            lt[(f4 * 4 + 3) * 72 + srow] = u3;
        }
        __syncthreads();
#pragma unroll
        for (int i = 0; i < 2; i++) {
            int G = i * 256 + t;
            int drow = G >> 3, g = G & 7;
            bf16x8 vv = *(const bf16x8*)(lt + drow * 72 + g * 8);
            *(bf16x8*)(xT + ((size_t)(b * DIM + d0 + drow) * SEQ + s0 + g * 8)) = vv;
        }
        return;
    }
    const int idx = bidx - 2048;
    if (idx == 128) {
        b2[t]       = bq[t];
        b2[t + 256] = bq[t + 256];
        b2[512 + t] = bk[t];
        b2[768 + t] = bk[t + 256];
        return;
    }
    const float* W = (idx < 64) ? Wq : Wk;
    const int nbase = (idx < 64) ? 0 : 512;
    const int w = idx & 63;
    const int kt = w & 7, nt = w >> 3;
    const int k0 = kt * 64, n0 = nt * 64;
#pragma unroll
    for (int i = 0; i < 4; i++) {
        int G = i * 256 + t;
        int krow = G >> 4, f4 = G & 15;
        const float4 v = *(const float4*)(W + ((size_t)(k0 + krow) * DIM + n0 + f4 * 4));
        lt[(f4 * 4 + 0) * 72 + krow] = f2bf(v.x);
        lt[(f4 * 4 + 1) * 72 + krow] = f2bf(v.y);
        lt[(f4 * 4 + 2) * 72 + krow] = f2bf(v.z);
        lt[(f4 * 4 + 3) * 72 + krow] = f2bf(v.w);
    }
    __syncthreads();
#pragma unroll
    for (int i = 0; i < 2; i++) {
        int G = i * 256 + t;
        int nrow = G >> 3, g = G & 7;
        bf16x8 vv = *(const bf16x8*)(lt + nrow * 72 + g * 8);
        *(bf16x8*)(W2 + ((size_t)(nbase + n0 + nrow) * DIM + k0 + g * 8)) = vv;
    }
}

// ---------------------------------------------------------------------------
// proj: C[16384 x 1024] = xbf @ W2^T + b2 ; 128x256 tile, 512 thr / 8 waves,
// BK=32, 3-stage ring (72 KB), vmcnt(3). grid (512) XCD-mapped.
// Q epilogue pre-scales by SCALE (R11).  [byte-identical: control]
// ---------------------------------------------------------------------------
__global__ __launch_bounds__(512, 4) void proj(const bf_t* __restrict__ xbf,
                                               const bf_t* __restrict__ W2,
                                               const float* __restrict__ b2,
                                               bf_t* __restrict__ Qb,
                                               bf_t* __restrict__ Kb) {
    __shared__ bf_t smem[36864];           // 72 KB: 3 x (A[128][32] | B[256][32])
    const int gid = blockIdx.x;
    const int xcd = gid & 7, rr = gid >> 3;
    const int bm = xcd * 16 + (rr >> 2), bn = rr & 3;
    const int m0 = bm * 128, n0 = bn * 256;
    const int t = threadIdx.x, w = t >> 6, lane = t & 63;
    const int col = lane & 15, quad = lane >> 4;
    const int wm = (w & 1) * 64, wn = (w >> 1) * 64;
    const int sA = (quad ^ ((col >> 1) & 3)) * 8;
    const int srow = t >> 2, sslot = t & 3;
    const int c0 = (sslot ^ ((srow >> 1) & 3)) * 8;
    bf_t *p0 = smem, *p1 = smem + 12288, *p2 = smem + 24576;
    auto stage = [&](int s, bf_t* db) {
        const int k0 = s * 32 + c0;
        GLDS(xbf + (size_t)(m0 + srow) * DIM + k0,       db + t * 8);
        GLDS(W2  + (size_t)(n0 + srow) * DIM + k0,       db + 4096 + t * 8);
        GLDS(W2  + (size_t)(n0 + 128 + srow) * DIM + k0, db + 8192 + t * 8);
    };
    stage(0, p0); stage(1, p1);
    floatx4 acc[16] = {};
    for (int kt = 0; kt < 16; kt++) {
        if (kt < 15) { asm volatile("s_waitcnt vmcnt(3) lgkmcnt(0)" ::: "memory"); }
        else         { asm volatile("s_waitcnt vmcnt(0) lgkmcnt(0)" ::: "memory"); }
        __builtin_amdgcn_s_barrier();
        if (kt < 14) stage(kt + 2, p2);
        const bf_t* as_ = p0;
        const bf_t* bs_ = p0 + 4096;
        bf16x8 af[4], bfr[4];
#pragma unroll
        for (int mt = 0; mt < 4; mt++)
            af[mt] = *(const bf16x8*)(as_ + (wm + mt * 16 + col) * 32 + sA);
#pragma unroll
        for (int nt = 0; nt < 4; nt++)
            bfr[nt] = *(const bf16x8*)(bs_ + (wn + nt * 16 + col) * 32 + sA);
#pragma unroll
        for (int mt = 0; mt < 4; mt++)
#pragma unroll
            for (int nt = 0; nt < 4; nt++)
                acc[mt * 4 + nt] = __builtin_amdgcn_mfma_f32_16x16x32_bf16(
                    af[mt], bfr[nt], acc[mt * 4 + nt], 0, 0, 0);
        bf_t* tp = p0; p0 = p1; p1 = p2; p2 = tp;
    }
    float bias[4];
#pragma unroll
    for (int nt = 0; nt < 4; nt++) bias[nt] = b2[n0 + wn + nt * 16 + col];
    const float sc = (bn < 2) ? SCALE : 1.0f;   // R11: pre-scale Q
    __syncthreads();
#pragma unroll
    for (int mt = 0; mt < 4; mt++)
#pragma unroll
        for (int nt = 0; nt < 4; nt++)
#pragma unroll
            for (int r = 0; r < 4; r++)
                smem[(wm + mt * 16 + quad * 4 + r) * 256 + wn + nt * 16 + col] =
                    f2bf((acc[mt * 4 + nt][r] + bias[nt]) * sc);
    __syncthreads();
    bf_t* dst = (bn < 2) ? Qb : Kb;
    const int nadj = (bn < 2) ? n0 : (n0 - 512);
#pragma unroll
    for (int i = 0; i < 8; i++) {
        int idx = (i * 512 + t) * 8;
        int row = idx >> 8, cg = idx & 255;
        *(bf16x8*)(dst + (size_t)(m0 + row) * DIM + nadj + cg) = *(const bf16x8*)(smem + idx);
    }
}

// ---------------------------------------------------------------------------
// scores: per batch S' = (Q*SCALE) K^T; 128x256 tile, 512 thr / 8 waves,
// BK=32, 3-stage ring, vmcnt(3). grid (1024) XCD supergroups.
// epilogue exp(s') -> P' bf16 + row sums l.  [R14-validated; reverted]
// ---------------------------------------------------------------------------
__global__ __launch_bounds__(512, 4) void scores(const bf_t* __restrict__ Qb,
                                                 const bf_t* __restrict__ Kb,
                                                 bf_t* __restrict__ P,
                                                 float* __restrict__ l) {
    __shared__ bf_t smem[36864];
    const int gid = blockIdx.x;
    const int xcd = gid & 7, rr = gid >> 3;
    const int j = rr & 15, h = rr >> 4;
    const int sup = xcd + 8 * h;
    const int b = sup >> 3, g = sup & 7;
    const int bm = (g & 3) * 4 + (j & 3);
    const int bn = (g >> 2) * 4 + (j >> 2);
    const int m0 = bm * 128, n0 = bn * 256;
    const int t = threadIdx.x, w = t >> 6, lane = t & 63;
    const int col = lane & 15, quad = lane >> 4;
    const int wm = (w & 1) * 64, wn = (w >> 1) * 64;
    const int sA = (quad ^ ((col >> 1) & 3)) * 8;
    const int srow = t >> 2, sslot = t & 3;
    const int c0 = (sslot ^ ((srow >> 1) & 3)) * 8;
    const bf_t* Ab = Qb + (size_t)b * SEQ * DIM;
    const bf_t* Bb = Kb + (size_t)b * SEQ * DIM;
    bf_t *p0 = smem, *p1 = smem + 12288, *p2 = smem + 24576;
    auto stage = [&](int s, bf_t* db) {
        const int k0 = s * 32 + c0;
        GLDS(Ab + (size_t)(m0 + srow) * DIM + k0,       db + t * 8);
        GLDS(Bb + (size_t)(n0 + srow) * DIM + k0,       db + 4096 + t * 8);
        GLDS(Bb + (size_t)(n0 + 128 + srow) * DIM + k0, db + 8192 + t * 8);
    };
    stage(0, p0); stage(1, p1);
    floatx4 acc[16] = {};
    for (int kt = 0; kt < 16; kt++) {
        if (kt < 15) { asm volatile("s_waitcnt vmcnt(3) lgkmcnt(0)" ::: "memory"); }
        else         { asm volatile("s_waitcnt vmcnt(0) lgkmcnt(0)" ::: "memory"); }
        __builtin_amdgcn_s_barrier();
        if (kt < 14) stage(kt + 2, p2);
        const bf_t* as_ = p0;
        const bf_t* bs_ = p0 + 4096;
        bf16x8 af[4], bfr[4];
#pragma unroll
        for (int mt = 0; mt < 4; mt++)
            af[mt] = *(const bf16x8*)(as_ + (wm + mt * 16 + col) * 32 + sA);
#pragma unroll
        for (int nt = 0; nt < 4; nt++)
            bfr[nt] = *(const bf16x8*)(bs_ + (wn + nt * 16 + col) * 32 + sA);
#pragma unroll
        for (int mt = 0; mt < 4; mt++)
#pragma unroll
            for (int nt = 0; nt < 4; nt++)
                acc[mt * 4 + nt] = __builtin_amdgcn_mfma_f32_16x16x32_bf16(
                    af[mt], bfr[nt], acc[mt * 4 + nt], 0, 0, 0);
        bf_t* tp = p0; p0 = p1; p1 = p2; p2 = tp;
    }
    float psum[4][4];
#pragma unroll
    for (int mt = 0; mt < 4; mt++)
#pragma unroll
        for (int r = 0; r < 4; r++) psum[mt][r] = 0.f;
    __syncthreads();
#pragma unroll
    for (int mt = 0; mt < 4; mt++)
#pragma unroll
        for (int nt = 0; nt < 4; nt++)
#pragma unroll
            for (int r = 0; r < 4; r++) {
                float e = __expf(acc[mt * 4 + nt][r]);
                bf_t hv = f2bf(e);
                smem[(wm + mt * 16 + quad * 4 + r) * 256 + wn + nt * 16 + col] = hv;
                psum[mt][r] += bf2f(hv);
            }
#pragma unroll
    for (int mt = 0; mt < 4; mt++)
#pragma unroll
        for (int r = 0; r < 4; r++) {
            float v = psum[mt][r];
            v += __shfl_xor(v, 1);
            v += __shfl_xor(v, 2);
            v += __shfl_xor(v, 4);
            v += __shfl_xor(v, 8);
            psum[mt][r] = v;
        }
    if (col == 0) {
#pragma unroll
        for (int mt = 0; mt < 4; mt++)
#pragma unroll
            for (int r = 0; r < 4; r++)
                atomicAdd(&l[(size_t)b * SEQ + m0 + wm + mt * 16 + quad * 4 + r],
                          psum[mt][r]);
    }
    __syncthreads();
#pragma unroll
    for (int i = 0; i < 8; i++) {
        int idx = (i * 512 + t) * 8;
        int row = idx >> 8, cg = idx & 255;
        *(bf16x8*)(P + (size_t)(b * SEQ + m0 + row) * SEQ + n0 + cg) =
            *(const bf16x8*)(smem + idx);
    }
}

// ---------------------------------------------------------------------------
// pv: per batch out = (P' @ x) / l  (M=2048, N=512, K=2048). B = xT (k-contig).
// R15: R12 geometry (256x128 tile, 8 waves 4Mx2N, BK=64, 3-stage 144KB ring,
// grid 256, b=gid&7) with phase-split schedule. [byte-identical: control]
// ---------------------------------------------------------------------------
__global__ __launch_bounds__(512, 1) void pv(const bf_t* __restrict__ P,
                                             const bf_t* __restrict__ xT,
                                             const float* __restrict__ l,
                                             float* __restrict__ out) {
    __shared__ bf_t smem[73728];           // 144 KB: 3 x 24576
    const int gid = blockIdx.x;
    const int b = gid & 7;
    const int inner = gid >> 3;            // [0,32)
    const int bm = inner >> 2, bn = inner & 3;
    const int m0 = bm * 256, n0 = bn * 128;
    const int t = threadIdx.x, w = t >> 6, lane = t & 63;
    const int col = lane & 15, quad = lane >> 4;
    const int wm = (w & 3) * 64, wn = (w >> 2) * 64;
    const int sA = (quad ^ (col & 7)) * 8;            // read slot, kc=0; kc=1 at ^32
    const int srow = t >> 3, sslot = t & 7;           // staging: row, slot
    const int c0 = (sslot ^ (srow & 7)) * 8;          // source chunk offset
    const bf_t* Ab = P  + (size_t)b * SEQ * SEQ;
    const bf_t* Bb = xT + (size_t)b * DIM * SEQ;
    auto stageA = [&](int s) {
        bf_t* db = smem + (s % 3) * 24576;
        const int k0 = s * 64 + c0;
        GLDS(Ab + (size_t)(m0 + srow) * SEQ + k0,        db + t * 8);
        GLDS(Ab + (size_t)(m0 + 64 + srow) * SEQ + k0,   db + 4096 + t * 8);
        GLDS(Ab + (size_t)(m0 + 128 + srow) * SEQ + k0,  db + 8192 + t * 8);
    };
    auto stageB = [&](int s) {
        bf_t* db = smem + (s % 3) * 24576;
        const int k0 = s * 64 + c0;
        GLDS(Ab + (size_t)(m0 + 192 + srow) * SEQ + k0,  db + 12288 + t * 8);
        GLDS(Bb + (size_t)(n0 + srow) * SEQ + k0,        db + 16384 + t * 8);
        GLDS(Bb + (size_t)(n0 + 64 + srow) * SEQ + k0,   db + 20480 + t * 8);
    };
    stageA(0); stageB(0); stageA(1); stageB(1);
    floatx4 acc[16] = {};

#define PV_PHASE(as_, bs_, KOFF, GLDS_SLICE, TRAIL_BARRIER)                    \
    {                                                                          \
        bf16x8 af[4], bfr[4];                                                  \
        _Pragma("unroll")                                                      \
        for (int mt = 0; mt < 4; mt++)                                         \
            af[mt] = *(const bf16x8*)((as_) + (wm + mt * 16 + col) * 64 +      \
                                      (sA ^ (KOFF)));                          \
        _Pragma("unroll")                                                      \
        for (int nt = 0; nt < 4; nt++)                                         \
            bfr[nt] = *(const bf16x8*)((bs_) + (wn + nt * 16 + col) * 64 +     \
                                       (sA ^ (KOFF)));                         \
        GLDS_SLICE;                                                            \
        __builtin_amdgcn_s_barrier();                                          \
        asm volatile("s_waitcnt lgkmcnt(0)" ::: "memory");                     \
        __builtin_amdgcn_sched_barrier(0);                                     \
        __builtin_amdgcn_s_setprio(1);                                         \
        _Pragma("unroll")                                                      \
        for (int mt = 0; mt < 4; mt++)                                         \
            _Pragma("unroll")                                                  \
            for (int nt = 0; nt < 4; nt++)                                     \
                acc[mt * 4 + nt] = __builtin_amdgcn_mfma_f32_16x16x32_bf16(    \
                    af[mt], bfr[nt], acc[mt * 4 + nt], 0, 0, 0);               \
        __builtin_amdgcn_s_setprio(0);                                         \
        if (TRAIL_BARRIER) __builtin_amdgcn_s_barrier();                       \
    }

    for (int k2 = 0; k2 < 16; k2++) {
        asm volatile("s_waitcnt vmcnt(6) lgkmcnt(0)" ::: "memory");
        __builtin_amdgcn_s_barrier();
        {
            const bf_t* as_ = smem + ((2 * k2) % 3) * 24576;
            const bf_t* bs_ = as_ + 16384;
            PV_PHASE(as_, bs_, 0,  { if (k2 < 15) stageA(2 * k2 + 2); }, 1)
            PV_PHASE(as_, bs_, 32, { if (k2 < 15) stageB(2 * k2 + 2); }, 0)
        }
        if (k2 < 15) { asm volatile("s_waitcnt vmcnt(6) lgkmcnt(0)" ::: "memory"); }
        else         { asm volatile("s_waitcnt vmcnt(0) lgkmcnt(0)" ::: "memory"); }
        __builtin_amdgcn_s_barrier();
        {
            const bf_t* as_ = smem + ((2 * k2 + 1) % 3) * 24576;
            const bf_t* bs_ = as_ + 16384;
            PV_PHASE(as_, bs_, 0,  { if (k2 < 15) stageA(2 * k2 + 3); }, 1)
            PV_PHASE(as_, bs_, 32, { if (k2 < 15) stageB(2 * k2 + 3); }, 0)
        }
    }
#undef PV_PHASE

    float inv[4][4];
#pragma unroll
    for (int mt = 0; mt < 4; mt++)
#pragma unroll
        for (int r = 0; r < 4; r++)
            inv[mt][r] = 1.0f / l[(size_t)b * SEQ + m0 + wm + mt * 16 + quad * 4 + r];
#pragma unroll
    for (int mt = 0; mt < 4; mt++)
#pragma unroll
        for (int nt = 0; nt < 4; nt++)
#pragma unroll
            for (int r = 0; r < 4; r++) {
                int row = m0 + wm + mt * 16 + quad * 4 + r;
                int cc  = n0 + wn + nt * 16 + col;
                float v = acc[mt * 4 + nt][r] * inv[mt][r];
                __builtin_nontemporal_store(v, &out[(size_t)(b * SEQ + row) * DIM + cc]);
            }
}

// ---------------------------------------------------------------------------
extern "C" void kernel_launch(void* const* d_in, const int* in_sizes, int n_in,
                              void* d_out, int out_size, void* d_ws, size_t ws_size,
                              hipStream_t stream) {
    (void)in_sizes; (void)n_in; (void)out_size;
    const float* x  = (const float*)d_in[0];
    const float* Wq = (const float*)d_in[1];
    const float* bq = (const float*)d_in[2];
    const float* Wk = (const float*)d_in[3];
    const float* bk = (const float*)d_in[4];
    float* out = (float*)d_out;

    char* ws = (char*)d_ws;
    const size_t SZ_XBF = (size_t)NB * SEQ * DIM * 2;   // 16.78 MB
    const size_t SZ_P   = (size_t)NB * SEQ * SEQ * 2;   // 67.1 MB
    bf_t* xbf = (bf_t*)(ws + 0);
    bf_t* xT  = (bf_t*)(ws + SZ_XBF);
    bf_t* Qb  = (bf_t*)(ws + 2 * SZ_XBF);
    bf_t* Kb  = (bf_t*)(ws + 3 * SZ_XBF);
    bf_t* P   = (bf_t*)(ws + 4 * SZ_XBF);
    bf_t* W2  = (bf_t*)(ws + 4 * SZ_XBF + SZ_P);
    float* b2 = (float*)(ws + 4 * SZ_XBF + SZ_P + 1024 * 512 * 2);
    float* l  = (float*)(ws + 4 * SZ_XBF + SZ_P + 1024 * 512 * 2 + 4096);
    const size_t NEED = 4 * SZ_XBF + SZ_P + 1024 * 512 * 2 + 4096 + (size_t)NB * SEQ * 4;
    if (ws_size < NEED) return;   // failure signature: absmax 0.1475 => ws too small

    hipMemsetAsync(l, 0, (size_t)NB * SEQ * 4, stream);
    prep<<<dim3(2177), dim3(256), 0, stream>>>(x, Wq, Wk, bq, bk, xbf, xT, W2, b2);
    proj<<<dim3(512), dim3(512), 0, stream>>>(xbf, W2, b2, Qb, Kb);
    scores<<<dim3(1024), dim3(512), 0, stream>>>(Qb, Kb, P, l);
    pv<<<dim3(256), dim3(512), 0, stream>>>(P, xT, l, out);
}